// Round 8
// baseline (349.583 us; speedup 1.0000x reference)
//
#include <hip/hip_runtime.h>
#include <stdint.h>

// Problem constants (match reference)
#define SLAB 8192    // SL
#define SUNL 16384   // SU
#define DIMX 1024
#define HID1 2048
#define HID2 512
#define KTRIES 8
#define MTOT (SLAB + SUNL)   // 24576

typedef __attribute__((ext_vector_type(8))) short bf16x8;    // 8 bf16 = 4 VGPRs
typedef __attribute__((ext_vector_type(4))) float f32x4;

// fp32 -> bf16 round-to-nearest-even
__device__ __forceinline__ unsigned short f2bf(float f) {
  union { float f; uint32_t u; } c; c.f = f;
  return (unsigned short)((c.u + 0x7fffu + ((c.u >> 16) & 1u)) >> 16);
}

// async global->LDS, 16B per lane; lds dest = wave-uniform base + lane*16
__device__ __forceinline__ void async16(const void* g, void* l) {
  __builtin_amdgcn_global_load_lds(
      (const __attribute__((address_space(1))) unsigned int*)g,
      (__attribute__((address_space(3))) unsigned int*)l,
      16, 0, 0);
}

// ---------------------------------------------------------------------------
// Threefry2x32 (JAX-compatible, 20 rounds)
// ---------------------------------------------------------------------------
struct U2 { uint32_t x, y; };

__device__ __forceinline__ U2 threefry(uint32_t k0, uint32_t k1, uint32_t x0, uint32_t x1) {
  uint32_t ks2 = k0 ^ k1 ^ 0x1BD11BDAu;
  x0 += k0; x1 += k1;
#define TF_R(r) { x0 += x1; x1 = (x1 << (r)) | (x1 >> (32 - (r))); x1 ^= x0; }
  TF_R(13) TF_R(15) TF_R(26) TF_R(6)
  x0 += k1; x1 += ks2 + 1u;
  TF_R(17) TF_R(29) TF_R(16) TF_R(24)
  x0 += ks2; x1 += k0 + 2u;
  TF_R(13) TF_R(15) TF_R(26) TF_R(6)
  x0 += k0; x1 += k1 + 3u;
  TF_R(17) TF_R(29) TF_R(16) TF_R(24)
  x0 += k1; x1 += ks2 + 4u;
  TF_R(13) TF_R(15) TF_R(26) TF_R(6)
  x0 += ks2; x1 += k0 + 5u;
#undef TF_R
  return {x0, x1};
}

// ---------------------------------------------------------------------------
// prep_kernel: one launch for cast(X_l|X_u), transpose-cast W1, W2, and pairs.
// ---------------------------------------------------------------------------
#define XL_BLOCKS (SLAB * DIMX / 4 / 256)           // 8192
#define CAST_BLOCKS (MTOT * DIMX / 4 / 256)         // 24576
#define T1_NBX (HID1 / 32)                          // 64
#define T1_BLOCKS ((HID1 / 32) * (DIMX / 32))       // 2048
#define T2_NBX (HID2 / 32)                          // 16
#define T2_BLOCKS ((HID2 / 32) * (HID1 / 32))       // 1024
#define PAIR_BLOCKS (SUNL / 256)                    // 64
#define PREP_BLOCKS (CAST_BLOCKS + T1_BLOCKS + T2_BLOCKS + PAIR_BLOCKS)

__global__ __launch_bounds__(256) void prep_kernel(
    const float* __restrict__ Xl, const float* __restrict__ Xu,
    const float* __restrict__ W1, const float* __restrict__ W2,
    const float* __restrict__ y_l, const float* __restrict__ y_u,
    unsigned short* __restrict__ X_bf, unsigned short* __restrict__ W1T,
    unsigned short* __restrict__ W2T,
    int* __restrict__ ia, int* __restrict__ ib, float* __restrict__ kv)
{
  __shared__ float t[32][33];
  int b = blockIdx.x;
  int tid = threadIdx.x;

  if (b < CAST_BLOCKS) {
    const float* src; size_t i, doff;
    if (b < XL_BLOCKS) { src = Xl; i = (size_t)b * 256 + tid; doff = 0; }
    else { src = Xu; i = (size_t)(b - XL_BLOCKS) * 256 + tid; doff = (size_t)SLAB * DIMX / 4; }
    float4 v = ((const float4*)src)[i];
    ushort4 o;
    o.x = f2bf(v.x); o.y = f2bf(v.y); o.z = f2bf(v.z); o.w = f2bf(v.w);
    ((ushort4*)X_bf)[doff + i] = o;
  } else if (b < CAST_BLOCKS + T1_BLOCKS + T2_BLOCKS) {
    const float* W; unsigned short* WT; int K, N, bx, by;
    if (b < CAST_BLOCKS + T1_BLOCKS) {
      int tb = b - CAST_BLOCKS;
      W = W1; WT = W1T; K = DIMX; N = HID1; bx = tb % T1_NBX; by = tb / T1_NBX;
    } else {
      int tb = b - CAST_BLOCKS - T1_BLOCKS;
      W = W2; WT = W2T; K = HID1; N = HID2; bx = tb % T2_NBX; by = tb / T2_NBX;
    }
    int k0 = by * 32, n0 = bx * 32;
    int tx = tid & 31, ty = tid >> 5;
#pragma unroll
    for (int i = 0; i < 32; i += 8)
      t[ty + i][tx] = W[(size_t)(k0 + ty + i) * N + n0 + tx];
    __syncthreads();
#pragma unroll
    for (int i = 0; i < 32; i += 8)
      WT[(size_t)(n0 + ty + i) * K + k0 + tx] = f2bf(t[tx][ty + i]);
  } else {
    // pair sampling (verified R1: partitionable threefry, bits1^bits2, &8191)
    int r = (b - CAST_BLOCKS - T1_BLOCKS - T2_BLOCKS) * 256 + tid;
    U2 ka  = threefry(0u, 42u, 0u, 0u);
    U2 kb  = threefry(0u, 42u, 0u, 1u);
    U2 k2a = threefry(ka.x, ka.y, 0u, 1u);
    U2 k2b = threefry(kb.x, kb.y, 0u, 1u);
    int iav[KTRIES], ibv[KTRIES];
#pragma unroll
    for (int c = 0; c < KTRIES; ++c) {
      uint32_t tt = (uint32_t)(r * KTRIES + c);
      U2 oa = threefry(k2a.x, k2a.y, 0u, tt);
      U2 ob = threefry(k2b.x, k2b.y, 0u, tt);
      iav[c] = (int)((oa.x ^ oa.y) & (SLAB - 1));
      ibv[c] = (int)((ob.x ^ ob.y) & (SLAB - 1));
    }
    int a = iav[0], bb2 = ibv[0];
#pragma unroll
    for (int c = 0; c < KTRIES; ++c) {
      if (iav[c] != ibv[c] && y_l[iav[c]] != y_l[ibv[c]]) { a = iav[c]; bb2 = ibv[c]; break; }
    }
    float ya = y_l[a], yb = y_l[bb2];
    ia[r] = a; ib[r] = bb2; kv[r] = (y_u[r] - yb) / (ya - yb);
  }
}

// ---------------------------------------------------------------------------
// bf16 MFMA GEMM, 128x256 tile, BK=32, 2 BLOCKS/CU (R8):
//   - R7 diagnosis: pipes balanced (MFMA 2480 ~ LDS 2300 cyc/tile-64/CU,
//     roofline ~50us GEMM1) but measured 107us = 46%: with 1 block/CU and
//     2 waves/SIMD running IDENTICAL code+barriers, every stall is
//     CU-wide. Fix = TLP: 256-thread blocks (4 waves, 2Mx2N, wave tile
//     64x128 = mirror of verified geometry), LDS 48 KB -> 2 independent
//     blocks/CU (96 KB LDS, 8 waves = 2/SIMD at ~244 regs). Per-CU pipe
//     totals unchanged (same FLOP/LDS-byte 43.7); barrier groups now
//     independent -> block B computes while block A waits.
//   - Also fixes GEMM2 grid: 192 -> 384 blocks (was idling 25% of CUs).
//   - Per tile-32 (R6-verified rotation, mirrored a<->b):
//       entry: {a0(2),b0(4)}@t outstanding (pre-issued); q4(t-1) pending
//       ph1: issue b1(4) | q4'(t-1) x8 | lgkm(4) [a0,b0 done] | q1 x8
//       ph2: issue a1(2) | lgkm(2) [b1 done] | q2 x8 | lgkm(0) BAR1
//       ph3: stage t+2 (6 calls: A 2, B 4) | q3 x8 | vmcnt(6) BAR2
//       ph4: pre-issue {a0,b0}@t+1 (6 reads, next buf)
//   - vmcnt ledger: 6 calls/tile; at vmcnt(6)@t queue = S@t-1(6)+S@t(6)
//     -> drains S@t-1 = t+1 resident. Prologue 12 calls, vmcnt(6) = t0
//     resident. Tail: vmcnt(0)@NT-2 -> NT-1 resident; NT-1 barrier-free.
//   - LDS 48 KB: As[2][4096] (128x32) + Bs[2][8192] (256x32), 64B rows.
//     Swizzle (R6-verified, 0 conflicts): slot = chunk ^ ((row>>1)&3);
//     read cs = (q ^ ((fr>>1)&3))<<3 lane-constant; staging source
//     pre-swizzled schunk = (tid&3)^((srow>>1)&3) (both sides, rule #21).
//   - Registers: acc[4][8] = 128 AGPR; frag pool 2 sets x 12 frags =
//     96 VGPR (same budget as R6/R7, no spill measured there).
//   - Per-acc-element K order ascending -> numerics unchanged.
//   - Epilogue j-innermost (R2-verified: WRITE_SIZE == output size).
// ---------------------------------------------------------------------------
#define GROUP_M 8
#define MFMA_B16(a, b, c) __builtin_amdgcn_mfma_f32_16x16x32_bf16(a, b, c, 0, 0, 0)
#define SBAR __builtin_amdgcn_sched_barrier(0)

template<bool QP, bool ST, int VMC, bool BARS, bool PRE>
__device__ __forceinline__ void ksub(
    const unsigned short* AsB, const unsigned short* BsB,   // read buf
    unsigned short* AsS, unsigned short* BsS,               // staging dest
    const unsigned short* AsP, const unsigned short* BsP,   // pre-issue buf
    const unsigned short* gA, const unsigned short* gB,
    int kk2, int K, int ldst, int ofsA, int ofsB,
    bf16x8 (&ha0)[2], bf16x8 (&hb0)[4],   // in: this tile a0,b0 (pre-issued)
    bf16x8 (&na0)[2], bf16x8 (&nb0)[4],   // out: next tile a0,b0
    bf16x8 (&ca1)[2], bf16x8 (&cb1)[4],   // in: prev tile a1,b1 (q4')
    bf16x8 (&ta1)[2], bf16x8 (&tb1)[4],   // out: this tile a1,b1
    f32x4 (&acc)[4][8])
{
  // ph1: issue b1(4) | q4'(prev) | lgkm(4) | q1
#pragma unroll
  for (int j = 0; j < 4; ++j)
    tb1[j] = *(const bf16x8*)(BsB + ofsB + (j + 4) * 512);
  SBAR;
  if (QP) {
    __builtin_amdgcn_s_setprio(1);
#pragma unroll
    for (int i = 0; i < 2; ++i)
#pragma unroll
      for (int j = 0; j < 4; ++j)
        acc[i + 2][j + 4] = MFMA_B16(ca1[i], cb1[j], acc[i + 2][j + 4]);
    __builtin_amdgcn_s_setprio(0);
    SBAR;
  }
  asm volatile("s_waitcnt lgkmcnt(4)" ::: "memory");   // a0,b0 done (b1 out)
  SBAR;
  __builtin_amdgcn_s_setprio(1);
#pragma unroll
  for (int i = 0; i < 2; ++i)
#pragma unroll
    for (int j = 0; j < 4; ++j)
      acc[i][j] = MFMA_B16(ha0[i], hb0[j], acc[i][j]);
  __builtin_amdgcn_s_setprio(0);
  SBAR;

  // ph2: issue a1(2) | lgkm(2) | q2 | lgkm(0)
#pragma unroll
  for (int i = 0; i < 2; ++i)
    ta1[i] = *(const bf16x8*)(AsB + ofsA + (i + 2) * 512);
  SBAR;
  asm volatile("s_waitcnt lgkmcnt(2)" ::: "memory");   // b1 done (a1 out)
  SBAR;
  __builtin_amdgcn_s_setprio(1);
#pragma unroll
  for (int i = 0; i < 2; ++i)
#pragma unroll
    for (int j = 0; j < 4; ++j)
      acc[i][j + 4] = MFMA_B16(ha0[i], tb1[j], acc[i][j + 4]);
  __builtin_amdgcn_s_setprio(0);
  asm volatile("s_waitcnt lgkmcnt(0)" ::: "memory");   // all cur reads done
  SBAR;
  if (BARS) __builtin_amdgcn_s_barrier();              // BAR1
  if (ST) {   // stage tile t+2 -> cur buf: A 2 calls + B 4 calls
    async16(gA + kk2,                  AsS + ldst);
    async16(gA + (size_t)64 * K + kk2, AsS + 2048 + ldst);
#pragma unroll
    for (int c = 0; c < 4; ++c)
      async16(gB + (size_t)(c * 64) * K + kk2, BsS + c * 2048 + ldst);
    SBAR;
  }
  // q3 (pure register; overlaps staging issue/DMA)
  __builtin_amdgcn_s_setprio(1);
#pragma unroll
  for (int i = 0; i < 2; ++i)
#pragma unroll
    for (int j = 0; j < 4; ++j)
      acc[i + 2][j] = MFMA_B16(ta1[i], hb0[j], acc[i + 2][j]);
  __builtin_amdgcn_s_setprio(0);
  if (VMC == 6)      asm volatile("s_waitcnt vmcnt(6)" ::: "memory");
  else if (VMC == 0) asm volatile("s_waitcnt vmcnt(0)" ::: "memory");
  if (BARS) __builtin_amdgcn_s_barrier();              // BAR2: t+1 resident

  // ph4: pre-issue next tile a0,b0 (drain under next q4'/q1)
  if (PRE) {
#pragma unroll
    for (int i = 0; i < 2; ++i)
      na0[i] = *(const bf16x8*)(AsP + ofsA + i * 512);
#pragma unroll
    for (int j = 0; j < 4; ++j)
      nb0[j] = *(const bf16x8*)(BsP + ofsB + j * 512);
    SBAR;
  }
}

template<int OUT_BF16, int RELU>
__global__ __launch_bounds__(256, 2) void gemm_bt_128(
    const unsigned short* __restrict__ A,   // [M][K] bf16
    const unsigned short* __restrict__ Bt,  // [N][K] bf16
    const float* __restrict__ bias,         // [N] fp32
    void* __restrict__ C0, void* __restrict__ C1, int Msplit,
    int M, int N, int K)
{
  __shared__ unsigned short As[2][4096];   // 2 x 128x32 bf16 = 16 KB
  __shared__ unsigned short Bs[2][8192];   // 2 x 256x32 bf16 = 32 KB

  const int tid  = threadIdx.x;
  const int wave = tid >> 6;
  const int lane = tid & 63;

  // L2 block swizzle (m-panels of 128 rows)
  const int nbx = N >> 8;
  const int gsize = nbx * GROUP_M;
  const int grp = blockIdx.x / gsize, within = blockIdx.x % gsize;
  const int m0 = (grp * GROUP_M + (within % GROUP_M)) << 7;
  const int n0 = (within / GROUP_M) << 8;

  const int wm = (wave >> 1) << 6;   // 0 / 64
  const int wn = (wave & 1) << 7;    // 0 / 128

  // staging lane geometry: call = 256 lanes x 16B = 64 rows x 64B
  // pre-swizzled chunk key = (row>>1)&3 (R6-verified: 0 conflicts)
  const int srow   = tid >> 2;                       // row within call (0..63)
  const int schunk = (tid & 3) ^ ((srow >> 1) & 3);  // pre-swizzled 16B chunk
  const unsigned short* gA = A  + (size_t)(m0 + srow) * K + schunk * 8;
  const unsigned short* gB = Bt + (size_t)(n0 + srow) * K + schunk * 8;
  const int ldst = wave << 9;                   // wave LDS slice (512 ushorts)

  // fragment read geometry: lane (fr,q) reads row ..+fr, k-chunk q;
  // stored slot = q ^ ((r>>1)&3) = q ^ ((fr>>1)&3)  (lane-constant)
  const int fr = lane & 15, q = lane >> 4;
  const int cs = (q ^ ((fr >> 1) & 3)) << 3;    // slot offset (ushorts)
  const int ofsA = ((wm + fr) << 5) + cs;
  const int ofsB = ((wn + fr) << 5) + cs;

  f32x4 acc[4][8] = {};
  bf16x8 a0A[2], b0A[4], a0B[2], b0B[4];   // head sets (pre-issued a0,b0)
  bf16x8 a1A[2], b1A[4], a1B[2], b1B[4];   // tail sets (q4 carry a1,b1)

  unsigned short* A0p = &As[0][0]; unsigned short* B0p = &Bs[0][0];
  unsigned short* A1p = &As[1][0]; unsigned short* B1p = &Bs[1][0];

  // prologue: stage tile0 -> buf0 (6 calls), tile1 -> buf1 (6 calls);
  // vmcnt(6) = tile0 resident, tile1 in flight (ledger invariant).
  async16(gA,                  A0p + ldst);
  async16(gA + (size_t)64 * K, A0p + 2048 + ldst);
#pragma unroll
  for (int c = 0; c < 4; ++c)
    async16(gB + (size_t)(c * 64) * K,      B0p + c * 2048 + ldst);
  async16(gA + 32,                  A1p + ldst);
  async16(gA + (size_t)64 * K + 32, A1p + 2048 + ldst);
#pragma unroll
  for (int c = 0; c < 4; ++c)
    async16(gB + (size_t)(c * 64) * K + 32, B1p + c * 2048 + ldst);
  asm volatile("s_waitcnt vmcnt(6)" ::: "memory");
  __builtin_amdgcn_s_barrier();
  // pre-issue a0,b0 of tile0 (6 reads, buf0)
#pragma unroll
  for (int i = 0; i < 2; ++i)
    a0A[i] = *(const bf16x8*)(A0p + ofsA + i * 512);
#pragma unroll
  for (int j = 0; j < 4; ++j)
    b0A[j] = *(const bf16x8*)(B0p + ofsB + j * 512);
  SBAR;

  const int NT = K >> 5;   // 32 (GEMM1) or 64 (GEMM2); even, >= 8

  // t = 0 (buf0): no q4' yet
  ksub<false, true, 6, true, true>(A0p, B0p, A0p, B0p, A1p, B1p, gA, gB,
      2 * 32, K, ldst, ofsA, ofsB,
      a0A, b0A, a0B, b0B, a1B, b1B, a1A, b1A, acc);
  // t = 1 .. NT-4 in pairs (buf1, buf0)
#pragma unroll 1
  for (int t = 1; t <= NT - 5; t += 2) {
    ksub<true, true, 6, true, true>(A1p, B1p, A1p, B1p, A0p, B0p, gA, gB,
        (t + 2) * 32, K, ldst, ofsA, ofsB,
        a0B, b0B, a0A, b0A, a1A, b1A, a1B, b1B, acc);
    ksub<true, true, 6, true, true>(A0p, B0p, A0p, B0p, A1p, B1p, gA, gB,
        (t + 3) * 32, K, ldst, ofsA, ofsB,
        a0A, b0A, a0B, b0B, a1B, b1B, a1A, b1A, acc);
  }
  // t = NT-3 (buf1): full, stages tile NT-1
  ksub<true, true, 6, true, true>(A1p, B1p, A1p, B1p, A0p, B0p, gA, gB,
      (NT - 1) * 32, K, ldst, ofsA, ofsB,
      a0B, b0B, a0A, b0A, a1A, b1A, a1B, b1B, acc);
  // t = NT-2 (buf0): no stage; vmcnt(0) -> tile NT-1 resident
  ksub<true, false, 0, true, true>(A0p, B0p, A0p, B0p, A1p, B1p, gA, gB,
      0, K, ldst, ofsA, ofsB,
      a0A, b0A, a0B, b0B, a1B, b1B, a1A, b1A, acc);
  // t = NT-1 (buf1): no staging/barriers/pre
  ksub<true, false, -1, false, false>(A1p, B1p, A1p, B1p, A0p, B0p, gA, gB,
      0, K, ldst, ofsA, ofsB,
      a0B, b0B, a0A, b0A, a1A, b1A, a1B, b1B, acc);
  // final q4 of tile NT-1 (tail set B)
  __builtin_amdgcn_s_setprio(1);
#pragma unroll
  for (int i = 0; i < 2; ++i)
#pragma unroll
    for (int j = 0; j < 4; ++j)
      acc[i + 2][j + 4] = MFMA_B16(a1B[i], b1B[j], acc[i + 2][j + 4]);
  __builtin_amdgcn_s_setprio(0);

  // epilogue: bias + optional relu; per-block output select (tile-aligned)
  // C/D layout: col = lane&15, row = (lane>>4)*4 + reg   [m89/m91 verified]
  // j INNERMOST: each output line completed in consecutive stores
  void* Cb = (m0 < Msplit) ? C0 : C1;
  const int mbase = (m0 < Msplit) ? m0 : (m0 - Msplit);
  const int crow = mbase + wm + (lane >> 4) * 4;
  const int ccol = n0 + wn + (lane & 15);
  float bv[8];
#pragma unroll
  for (int j = 0; j < 8; ++j) bv[j] = bias[ccol + j * 16];
#pragma unroll
  for (int i = 0; i < 4; ++i) {
#pragma unroll
    for (int r = 0; r < 4; ++r) {
      size_t base = (size_t)(crow + i * 16 + r) * N + ccol;
#pragma unroll
      for (int j = 0; j < 8; ++j) {
        float v = acc[i][j][r] + bv[j];
        if (RELU) v = fmaxf(v, 0.0f);
        if (OUT_BF16) ((unsigned short*)Cb)[base + j * 16] = f2bf(v);
        else          ((float*)Cb)[base + j * 16] = v;
      }
    }
  }
}

// ---------------------------------------------------------------------------
// post_kernel: comb (blocks [0, SUNL/2)) + yhat (blocks [SUNL/2, +SLAB/4))
// ---------------------------------------------------------------------------
#define COMB_BLOCKS (SUNL / 2)              // 8192
#define YHAT_BLOCKS (SLAB / 4)              // 2048
#define POST_BLOCKS (COMB_BLOCKS + YHAT_BLOCKS)

__global__ __launch_bounds__(256) void post_kernel(
    const float* __restrict__ feat_l, const float* __restrict__ W3,
    const float* __restrict__ b3, const int* __restrict__ ia,
    const int* __restrict__ ib, const float* __restrict__ kv,
    float* __restrict__ out_comb, float* __restrict__ out_yhat)
{
  int b = blockIdx.x;
  if (b < COMB_BLOCKS) {
    int row = b * 2 + (threadIdx.x >> 7);
    int c = (threadIdx.x & 127) << 2;
    float k = kv[row];
    float km1 = 1.0f - k;
    float4 fa = *(const float4*)(feat_l + (size_t)ia[row] * HID2 + c);
    float4 fb = *(const float4*)(feat_l + (size_t)ib[row] * HID2 + c);
    float4 o;
    o.x = k * fa.x + km1 * fb.x;
    o.y = k * fa.y + km1 * fb.y;
    o.z = k * fa.z + km1 * fb.z;
    o.w = k * fa.w + km1 * fb.w;
    *(float4*)(out_comb + (size_t)row * HID2 + c) = o;
  } else {
    int wave = threadIdx.x >> 6;
    int lane = threadIdx.x & 63;
    int row = (b - COMB_BLOCKS) * 4 + wave;
    const float* f = feat_l + (size_t)row * HID2;
    float s = 0.f;
#pragma unroll
    for (int j = 0; j < HID2 / 64; ++j) s = fmaf(f[lane + j * 64], W3[lane + j * 64], s);
#pragma unroll
    for (int off = 32; off; off >>= 1) s += __shfl_down(s, off);
    if (lane == 0) out_yhat[row] = s + b3[0];
  }
}

// ---------------------------------------------------------------------------
extern "C" void kernel_launch(void* const* d_in, const int* in_sizes, int n_in,
                              void* d_out, int out_size, void* d_ws, size_t ws_size,
                              hipStream_t stream)
{
  const float* X_l = (const float*)d_in[0];
  const float* y_l = (const float*)d_in[1];
  const float* X_u = (const float*)d_in[2];
  const float* y_u = (const float*)d_in[3];
  const float* W1  = (const float*)d_in[4];
  const float* b1  = (const float*)d_in[5];
  const float* W2  = (const float*)d_in[6];
  const float* b2  = (const float*)d_in[7];
  const float* W3  = (const float*)d_in[8];
  const float* b3  = (const float*)d_in[9];

  float* out_featu = (float*)d_out;
  float* out_comb  = out_featu + (size_t)SUNL * HID2;
  float* out_yhat  = out_comb + (size_t)SUNL * HID2;

  // Workspace (~174 MB): X_bf = [Xl|Xu] contig, H_bf = [Hl|Hu] contig
  unsigned short* X_bf  = (unsigned short*)d_ws;                 // [24576][1024]
  unsigned short* W1T   = X_bf + (size_t)MTOT * DIMX;
  unsigned short* W2T   = W1T + (size_t)HID1 * DIMX;
  unsigned short* H_bf  = W2T + (size_t)HID2 * HID1;             // [24576][2048]
  float* feat_l = (float*)(H_bf + (size_t)MTOT * HID1);
  int*   ai = (int*)(feat_l + (size_t)SLAB * HID2);
  int*   bi = ai + SUNL;
  float* kv = (float*)(bi + SUNL);

  prep_kernel<<<dim3(PREP_BLOCKS), dim3(256), 0, stream>>>(
      X_l, X_u, W1, W2, y_l, y_u, X_bf, W1T, W2T, ai, bi, kv);

  // layer 1 (merged l+u): H = relu(X @ W1 + b1) -> bf16  [1536 blocks x 256]
  gemm_bt_128<1, 1><<<dim3((HID1 / 256) * (MTOT / 128)), dim3(256), 0, stream>>>(
      X_bf, W1T, b1, H_bf, H_bf, MTOT /*no split*/, MTOT, HID1, DIMX);

  // layer 2 (merged l+u): feat = relu(H @ W2 + b2) -> fp32, split dest [384 blocks]
  gemm_bt_128<0, 1><<<dim3((HID2 / 256) * (MTOT / 128)), dim3(256), 0, stream>>>(
      H_bf, W2T, b2, feat_l, out_featu, SLAB, MTOT, HID2, HID1);

  post_kernel<<<dim3(POST_BLOCKS), dim3(256), 0, stream>>>(
      feat_l, W3, b3, ai, bi, kv, out_comb, out_yhat);
}

// Round 9
// 324.728 us; speedup vs baseline: 1.0765x; 1.0765x over previous
//
#include <hip/hip_runtime.h>
#include <stdint.h>

// Problem constants (match reference)
#define SLAB 8192    // SL
#define SUNL 16384   // SU
#define DIMX 1024
#define HID1 2048
#define HID2 512
#define KTRIES 8
#define MTOT (SLAB + SUNL)   // 24576

typedef __attribute__((ext_vector_type(8))) short bf16x8;    // 8 bf16 = 4 VGPRs
typedef __attribute__((ext_vector_type(4))) float f32x4;

// fp32 -> bf16 round-to-nearest-even
__device__ __forceinline__ unsigned short f2bf(float f) {
  union { float f; uint32_t u; } c; c.f = f;
  return (unsigned short)((c.u + 0x7fffu + ((c.u >> 16) & 1u)) >> 16);
}

// async global->LDS, 16B per lane; lds dest = wave-uniform base + lane*16
__device__ __forceinline__ void async16(const void* g, void* l) {
  __builtin_amdgcn_global_load_lds(
      (const __attribute__((address_space(1))) unsigned int*)g,
      (__attribute__((address_space(3))) unsigned int*)l,
      16, 0, 0);
}

// ---------------------------------------------------------------------------
// Threefry2x32 (JAX-compatible, 20 rounds)
// ---------------------------------------------------------------------------
struct U2 { uint32_t x, y; };

__device__ __forceinline__ U2 threefry(uint32_t k0, uint32_t k1, uint32_t x0, uint32_t x1) {
  uint32_t ks2 = k0 ^ k1 ^ 0x1BD11BDAu;
  x0 += k0; x1 += k1;
#define TF_R(r) { x0 += x1; x1 = (x1 << (r)) | (x1 >> (32 - (r))); x1 ^= x0; }
  TF_R(13) TF_R(15) TF_R(26) TF_R(6)
  x0 += k1; x1 += ks2 + 1u;
  TF_R(17) TF_R(29) TF_R(16) TF_R(24)
  x0 += ks2; x1 += k0 + 2u;
  TF_R(13) TF_R(15) TF_R(26) TF_R(6)
  x0 += k0; x1 += k1 + 3u;
  TF_R(17) TF_R(29) TF_R(16) TF_R(24)
  x0 += k1; x1 += ks2 + 4u;
  TF_R(13) TF_R(15) TF_R(26) TF_R(6)
  x0 += ks2; x1 += k0 + 5u;
#undef TF_R
  return {x0, x1};
}

// ---------------------------------------------------------------------------
// prep_kernel: one launch for cast(X_l|X_u), transpose-cast W1, W2, and pairs.
// ---------------------------------------------------------------------------
#define XL_BLOCKS (SLAB * DIMX / 4 / 256)           // 8192
#define CAST_BLOCKS (MTOT * DIMX / 4 / 256)         // 24576
#define T1_NBX (HID1 / 32)                          // 64
#define T1_BLOCKS ((HID1 / 32) * (DIMX / 32))       // 2048
#define T2_NBX (HID2 / 32)                          // 16
#define T2_BLOCKS ((HID2 / 32) * (HID1 / 32))       // 1024
#define PAIR_BLOCKS (SUNL / 256)                    // 64
#define PREP_BLOCKS (CAST_BLOCKS + T1_BLOCKS + T2_BLOCKS + PAIR_BLOCKS)

__global__ __launch_bounds__(256) void prep_kernel(
    const float* __restrict__ Xl, const float* __restrict__ Xu,
    const float* __restrict__ W1, const float* __restrict__ W2,
    const float* __restrict__ y_l, const float* __restrict__ y_u,
    unsigned short* __restrict__ X_bf, unsigned short* __restrict__ W1T,
    unsigned short* __restrict__ W2T,
    int* __restrict__ ia, int* __restrict__ ib, float* __restrict__ kv)
{
  __shared__ float t[32][33];
  int b = blockIdx.x;
  int tid = threadIdx.x;

  if (b < CAST_BLOCKS) {
    const float* src; size_t i, doff;
    if (b < XL_BLOCKS) { src = Xl; i = (size_t)b * 256 + tid; doff = 0; }
    else { src = Xu; i = (size_t)(b - XL_BLOCKS) * 256 + tid; doff = (size_t)SLAB * DIMX / 4; }
    float4 v = ((const float4*)src)[i];
    ushort4 o;
    o.x = f2bf(v.x); o.y = f2bf(v.y); o.z = f2bf(v.z); o.w = f2bf(v.w);
    ((ushort4*)X_bf)[doff + i] = o;
  } else if (b < CAST_BLOCKS + T1_BLOCKS + T2_BLOCKS) {
    const float* W; unsigned short* WT; int K, N, bx, by;
    if (b < CAST_BLOCKS + T1_BLOCKS) {
      int tb = b - CAST_BLOCKS;
      W = W1; WT = W1T; K = DIMX; N = HID1; bx = tb % T1_NBX; by = tb / T1_NBX;
    } else {
      int tb = b - CAST_BLOCKS - T1_BLOCKS;
      W = W2; WT = W2T; K = HID1; N = HID2; bx = tb % T2_NBX; by = tb / T2_NBX;
    }
    int k0 = by * 32, n0 = bx * 32;
    int tx = tid & 31, ty = tid >> 5;
#pragma unroll
    for (int i = 0; i < 32; i += 8)
      t[ty + i][tx] = W[(size_t)(k0 + ty + i) * N + n0 + tx];
    __syncthreads();
#pragma unroll
    for (int i = 0; i < 32; i += 8)
      WT[(size_t)(n0 + ty + i) * K + k0 + tx] = f2bf(t[tx][ty + i]);
  } else {
    // pair sampling (verified R1: partitionable threefry, bits1^bits2, &8191)
    int r = (b - CAST_BLOCKS - T1_BLOCKS - T2_BLOCKS) * 256 + tid;
    U2 ka  = threefry(0u, 42u, 0u, 0u);
    U2 kb  = threefry(0u, 42u, 0u, 1u);
    U2 k2a = threefry(ka.x, ka.y, 0u, 1u);
    U2 k2b = threefry(kb.x, kb.y, 0u, 1u);
    int iav[KTRIES], ibv[KTRIES];
#pragma unroll
    for (int c = 0; c < KTRIES; ++c) {
      uint32_t tt = (uint32_t)(r * KTRIES + c);
      U2 oa = threefry(k2a.x, k2a.y, 0u, tt);
      U2 ob = threefry(k2b.x, k2b.y, 0u, tt);
      iav[c] = (int)((oa.x ^ oa.y) & (SLAB - 1));
      ibv[c] = (int)((ob.x ^ ob.y) & (SLAB - 1));
    }
    int a = iav[0], bb2 = ibv[0];
#pragma unroll
    for (int c = 0; c < KTRIES; ++c) {
      if (iav[c] != ibv[c] && y_l[iav[c]] != y_l[ibv[c]]) { a = iav[c]; bb2 = ibv[c]; break; }
    }
    float ya = y_l[a], yb = y_l[bb2];
    ia[r] = a; ib[r] = bb2; kv[r] = (y_u[r] - yb) / (ya - yb);
  }
}

// ---------------------------------------------------------------------------
// bf16 MFMA GEMM, 256x256 tile, BK=64 (two BK=32 sub-steps), R9 =
// R7 structure, COMPILER-SCHEDULED inner loop:
//   - R7/R8 lesson: the hand-gated schedule (sched_barrier(0) pins +
//     coarse counted lgkm before each MFMA quadrant) produced FULLY SERIAL
//     pipe use: wall 5350 cyc/tile-64/CU = MFMA 2480 + LDS 2300 + sync,
//     MfmaUtil 41%. This is the m141 failure mode (SBAR pinning defeats
//     the compiler's incremental lgkmcnt scheduling; m97 asm shows the
//     compiler emits lgkmcnt(4/3/1/0) per dependent MFMA on its own).
//   - R9 strips ALL sched_barrier(0), ALL counted lgkm gates, and setprio;
//     ds_reads are compiler-visible loads so dependencies are tracked
//     exactly and MFMAs can start as soon as their own operands land.
//   - Kept (compiler cannot derive these):
//     * lgkmcnt(0)+"memory" before BAR1: cross-wave -- all waves must have
//       DRAINED their cur-buf reads before any wave's staging overwrites.
//     * counted vmcnt(8) once per tile + BAR2: global_load_lds DMA ->
//       LDS residency ledger (queue = S@t-1(8)+S@t(8); drains S@t-1 ->
//       tile t+1 resident). Prologue 16 calls, vmcnt(8) = tile0 resident.
//       Tail: vmcnt(0)@NT-2 -> NT-1 resident; NT-1 barrier-free.
//     * program order as a scheduling hint: q4'(prev) rotation first,
//       pre-issued {a0,b0}, staged reads one cluster ahead.
//   - Memory ops cannot cross the "memory"-clobber asm -> buffer hazards
//     sound; per-acc-element MFMA chains are data-dependent -> order
//     unchanged -> bit-identical output.
//   - LDS 128 KB: As/Bs[2][16384] = 256 rows x 64 cols bf16 (128B rows).
//     Swizzle (R2/R7-verified, 0 conflicts): slot = c16 ^ (row&7);
//     read cs0 = (q ^ (fr&7))<<3, sub1 = ^32; staging source pre-swizzled
//     schunk = (tid&7)^(srow&7) (both sides, rule #21).
//   - Epilogue j-innermost (R2-verified: WRITE_SIZE == output size).
// ---------------------------------------------------------------------------
#define GROUP_M 8
#define MFMA_B16(a, b, c) __builtin_amdgcn_mfma_f32_16x16x32_bf16(a, b, c, 0, 0, 0)

template<bool QP, bool BARS, bool ST, int VMC, bool PRE>
__device__ __forceinline__ void ksub(
    const unsigned short* AsB, const unsigned short* BsB,   // read buf
    unsigned short* AsS, unsigned short* BsS,               // staging dest
    const unsigned short* AsP, const unsigned short* BsP,   // pre-issue buf
    const unsigned short* gA, const unsigned short* gB,
    int kk2, int K, int ldst,
    int ofsA, int ofsB, int ofsAp, int ofsBp,
    bf16x8 (&ha0)[4], bf16x8 (&hb0)[2],   // in: this sub a0,b0 (pre-issued)
    bf16x8 (&na0)[4], bf16x8 (&nb0)[2],   // out: next sub a0,b0
    bf16x8 (&ca1)[4], bf16x8 (&cb1)[2],   // in: prev sub a1,b1 (q4')
    bf16x8 (&ta1)[4], bf16x8 (&tb1)[2],   // out: this sub a1,b1
    f32x4 (&acc)[8][4])
{
  // issue b1 reads; q4'(prev) runs on registers meanwhile
#pragma unroll
  for (int j = 0; j < 2; ++j)
    tb1[j] = *(const bf16x8*)(BsB + ofsB + (j + 2) * 1024);
  if (QP) {
#pragma unroll
    for (int i = 0; i < 4; ++i)
#pragma unroll
      for (int j = 0; j < 2; ++j)
        acc[i + 4][j + 2] = MFMA_B16(ca1[i], cb1[j], acc[i + 4][j + 2]);
  }
  // q1: a0 x b0 (operands pre-issued last sub; compiler inserts exact waits)
#pragma unroll
  for (int i = 0; i < 4; ++i)
#pragma unroll
    for (int j = 0; j < 2; ++j)
      acc[i][j] = MFMA_B16(ha0[i], hb0[j], acc[i][j]);

  // issue a1 reads; q2: a0 x b1
#pragma unroll
  for (int i = 0; i < 4; ++i)
    ta1[i] = *(const bf16x8*)(AsB + ofsA + (i + 4) * 1024);
#pragma unroll
  for (int i = 0; i < 4; ++i)
#pragma unroll
    for (int j = 0; j < 2; ++j)
      acc[i][j + 2] = MFMA_B16(ha0[i], tb1[j], acc[i][j + 2]);

  if (BARS) {
    // all cur-buf reads must be DRAINED (not just issued) before any
    // wave's staging overwrites cur -- cross-wave, compiler can't derive
    asm volatile("s_waitcnt lgkmcnt(0)" ::: "memory");
    __builtin_amdgcn_s_barrier();              // BAR1
  }
  if (ST) {
#pragma unroll
    for (int c = 0; c < 4; ++c) {
      async16(gA + (size_t)(c * 64) * K + kk2, AsS + c * 4096 + ldst);
      async16(gB + (size_t)(c * 64) * K + kk2, BsS + c * 4096 + ldst);
    }
  }
  // q3: a1 x b0 (overlaps staging issue/DMA)
#pragma unroll
  for (int i = 0; i < 4; ++i)
#pragma unroll
    for (int j = 0; j < 2; ++j)
      acc[i + 4][j] = MFMA_B16(ta1[i], hb0[j], acc[i + 4][j]);
  if (VMC == 8)      asm volatile("s_waitcnt vmcnt(8)" ::: "memory");
  else if (VMC == 0) asm volatile("s_waitcnt vmcnt(0)" ::: "memory");
  if (BARS) __builtin_amdgcn_s_barrier();      // BAR2: tile t+1 resident

  // pre-issue next sub's a0,b0 (drain under next q4'/q1)
  if (PRE) {
#pragma unroll
    for (int i = 0; i < 4; ++i)
      na0[i] = *(const bf16x8*)(AsP + ofsAp + i * 1024);
#pragma unroll
    for (int j = 0; j < 2; ++j)
      nb0[j] = *(const bf16x8*)(BsP + ofsBp + j * 1024);
  }
}

template<int OUT_BF16, int RELU>
__global__ __launch_bounds__(512, 2) void gemm_bt_256(
    const unsigned short* __restrict__ A,   // [M][K] bf16
    const unsigned short* __restrict__ Bt,  // [N][K] bf16
    const float* __restrict__ bias,         // [N] fp32
    void* __restrict__ C0, void* __restrict__ C1, int Msplit,
    int M, int N, int K)
{
  __shared__ unsigned short As[2][16384];   // 2 x 256x64 bf16 = 64 KB
  __shared__ unsigned short Bs[2][16384];   // 64 KB

  const int tid  = threadIdx.x;
  const int wave = tid >> 6;
  const int lane = tid & 63;

  // L2 block swizzle (m-panels of 256 rows)
  const int nbx = N >> 8;
  const int gsize = nbx * GROUP_M;
  const int grp = blockIdx.x / gsize, within = blockIdx.x % gsize;
  const int m0 = (grp * GROUP_M + (within % GROUP_M)) << 8;
  const int n0 = (within / GROUP_M) << 8;

  const int wm = (wave >> 2) << 7;   // 0 / 128
  const int wn = (wave & 3) << 6;    // 0 / 64 / 128 / 192

  // staging lane geometry: call = 512 lanes x 16B = 64 rows x 128B
  // pre-swizzled chunk (R2-verified, 0 conflicts): key = row&7 over 8 chunks
  const int srow   = tid >> 3;                  // row within call (0..63)
  const int schunk = (tid & 7) ^ (srow & 7);    // pre-swizzled 16B chunk
  const unsigned short* gA = A  + (size_t)(m0 + srow) * K + schunk * 8;
  const unsigned short* gB = Bt + (size_t)(n0 + srow) * K + schunk * 8;
  const int ldst = wave << 9;                   // wave LDS slice (ushorts)

  // fragment read geometry: lane (fr,q), sub k-half s: chunk = q + 4s,
  // slot = chunk ^ (fr&7); sub1 offset = sub0 ^ 32 (ushorts)
  const int fr = lane & 15, q = lane >> 4;
  const int cs0 = (q ^ (fr & 7)) << 3;
  const int ofsA0 = ((wm + fr) << 6) + cs0;
  const int ofsB0 = ((wn + fr) << 6) + cs0;
  const int ofsA1 = ofsA0 ^ 32;
  const int ofsB1 = ofsB0 ^ 32;

  f32x4 acc[8][4] = {};
  bf16x8 a0A[4], b0A[2], a0B[4], b0B[2];   // head sets (pre-issued a0,b0)
  bf16x8 a1A[4], b1A[2], a1B[4], b1B[2];   // tail sets (q4 carry a1,b1)

  unsigned short* A0p = &As[0][0]; unsigned short* B0p = &Bs[0][0];
  unsigned short* A1p = &As[1][0]; unsigned short* B1p = &Bs[1][0];

  // prologue: stage tile0 -> buf0 (8 calls), tile1 -> buf1 (8 calls);
  // vmcnt(8) = tile0 resident, tile1 in flight (ledger invariant).
#pragma unroll
  for (int c = 0; c < 4; ++c) {
    async16(gA + (size_t)(c * 64) * K,      A0p + c * 4096 + ldst);
    async16(gB + (size_t)(c * 64) * K,      B0p + c * 4096 + ldst);
  }
#pragma unroll
  for (int c = 0; c < 4; ++c) {
    async16(gA + (size_t)(c * 64) * K + 64, A1p + c * 4096 + ldst);
    async16(gB + (size_t)(c * 64) * K + 64, B1p + c * 4096 + ldst);
  }
  asm volatile("s_waitcnt vmcnt(8)" ::: "memory");
  __builtin_amdgcn_s_barrier();
  // pre-issue a0,b0 of tile0 sub0 (buf0)
#pragma unroll
  for (int i = 0; i < 4; ++i)
    a0A[i] = *(const bf16x8*)(A0p + ofsA0 + i * 1024);
#pragma unroll
  for (int j = 0; j < 2; ++j)
    b0A[j] = *(const bf16x8*)(B0p + ofsB0 + j * 1024);

  const int NT = K >> 6;   // 16 (GEMM1) or 32 (GEMM2); even, >= 6

  // t = 0 (buf0): sub0 has no q4' yet
  ksub<false, false, false, -1, true>(A0p, B0p, A0p, B0p, A0p, B0p, gA, gB,
      0, K, ldst, ofsA0, ofsB0, ofsA1, ofsB1,
      a0A, b0A, a0B, b0B, a1B, b1B, a1A, b1A, acc);
  ksub<true, true, true, 8, true>(A0p, B0p, A0p, B0p, A1p, B1p, gA, gB,
      2 * 64, K, ldst, ofsA1, ofsB1, ofsA0, ofsB0,
      a0B, b0B, a0A, b0A, a1A, b1A, a1B, b1B, acc);

  // t = 1 .. NT-4 in pairs (buf1, buf0)
#pragma unroll 1
  for (int t = 1; t <= NT - 4; t += 2) {
    ksub<true, false, false, -1, true>(A1p, B1p, A1p, B1p, A1p, B1p, gA, gB,
        0, K, ldst, ofsA0, ofsB0, ofsA1, ofsB1,
        a0A, b0A, a0B, b0B, a1B, b1B, a1A, b1A, acc);
    ksub<true, true, true, 8, true>(A1p, B1p, A1p, B1p, A0p, B0p, gA, gB,
        (t + 2) * 64, K, ldst, ofsA1, ofsB1, ofsA0, ofsB0,
        a0B, b0B, a0A, b0A, a1A, b1A, a1B, b1B, acc);
    ksub<true, false, false, -1, true>(A0p, B0p, A0p, B0p, A0p, B0p, gA, gB,
        0, K, ldst, ofsA0, ofsB0, ofsA1, ofsB1,
        a0A, b0A, a0B, b0B, a1B, b1B, a1A, b1A, acc);
    ksub<true, true, true, 8, true>(A0p, B0p, A0p, B0p, A1p, B1p, gA, gB,
        (t + 3) * 64, K, ldst, ofsA1, ofsB1, ofsA0, ofsB0,
        a0B, b0B, a0A, b0A, a1A, b1A, a1B, b1B, acc);
  }
  // t = NT-3 (buf1): full, stages tile NT-1
  ksub<true, false, false, -1, true>(A1p, B1p, A1p, B1p, A1p, B1p, gA, gB,
      0, K, ldst, ofsA0, ofsB0, ofsA1, ofsB1,
      a0A, b0A, a0B, b0B, a1B, b1B, a1A, b1A, acc);
  ksub<true, true, true, 8, true>(A1p, B1p, A1p, B1p, A0p, B0p, gA, gB,
      (NT - 1) * 64, K, ldst, ofsA1, ofsB1, ofsA0, ofsB0,
      a0B, b0B, a0A, b0A, a1A, b1A, a1B, b1B, acc);
  // t = NT-2 (buf0): no stage; vmcnt(0) -> tile NT-1 resident
  ksub<true, false, false, -1, true>(A0p, B0p, A0p, B0p, A0p, B0p, gA, gB,
      0, K, ldst, ofsA0, ofsB0, ofsA1, ofsB1,
      a0A, b0A, a0B, b0B, a1B, b1B, a1A, b1A, acc);
  ksub<true, true, false, 0, true>(A0p, B0p, A0p, B0p, A1p, B1p, gA, gB,
      0, K, ldst, ofsA1, ofsB1, ofsA0, ofsB0,
      a0B, b0B, a0A, b0A, a1A, b1A, a1B, b1B, acc);
  // t = NT-1 (buf1): no barriers/staging
  ksub<true, false, false, -1, true>(A1p, B1p, A1p, B1p, A1p, B1p, gA, gB,
      0, K, ldst, ofsA0, ofsB0, ofsA1, ofsB1,
      a0A, b0A, a0B, b0B, a1B, b1B, a1A, b1A, acc);
  ksub<true, false, false, -1, false>(A1p, B1p, A1p, B1p, A1p, B1p, gA, gB,
      0, K, ldst, ofsA1, ofsB1, ofsA0, ofsB0,
      a0B, b0B, a0A, b0A, a1A, b1A, a1B, b1B, acc);
  // final q4 of last sub (tail set B)
#pragma unroll
  for (int i = 0; i < 4; ++i)
#pragma unroll
    for (int j = 0; j < 2; ++j)
      acc[i + 4][j + 2] = MFMA_B16(a1B[i], b1B[j], acc[i + 4][j + 2]);

  // epilogue: bias + optional relu; per-block output select (tile-aligned)
  // C/D layout: col = lane&15, row = (lane>>4)*4 + reg   [m89/m91 verified]
  // j INNERMOST: each 128B output line completed in 4 consecutive stores
  void* Cb = (m0 < Msplit) ? C0 : C1;
  const int mbase = (m0 < Msplit) ? m0 : (m0 - Msplit);
  const int crow = mbase + wm + (lane >> 4) * 4;
  const int ccol = n0 + wn + (lane & 15);
  float bv[4];
#pragma unroll
  for (int j = 0; j < 4; ++j) bv[j] = bias[ccol + j * 16];
#pragma unroll
  for (int i = 0; i < 8; ++i) {
#pragma unroll
    for (int r = 0; r < 4; ++r) {
      size_t base = (size_t)(crow + i * 16 + r) * N + ccol;
#pragma unroll
      for (int j = 0; j < 4; ++j) {
        float v = acc[i][j][r] + bv[j];
        if (RELU) v = fmaxf(v, 0.0f);
        if (OUT_BF16) ((unsigned short*)Cb)[base + j * 16] = f2bf(v);
        else          ((float*)Cb)[base + j * 16] = v;
      }
    }
  }
}

// ---------------------------------------------------------------------------
// post_kernel: comb (blocks [0, SUNL/2)) + yhat (blocks [SUNL/2, +SLAB/4))
// ---------------------------------------------------------------------------
#define COMB_BLOCKS (SUNL / 2)              // 8192
#define YHAT_BLOCKS (SLAB / 4)              // 2048
#define POST_BLOCKS (COMB_BLOCKS + YHAT_BLOCKS)

__global__ __launch_bounds__(256) void post_kernel(
    const float* __restrict__ feat_l, const float* __restrict__ W3,
    const float* __restrict__ b3, const int* __restrict__ ia,
    const int* __restrict__ ib, const float* __restrict__ kv,
    float* __restrict__ out_comb, float* __restrict__ out_yhat)
{
  int b = blockIdx.x;
  if (b < COMB_BLOCKS) {
    int row = b * 2 + (threadIdx.x >> 7);
    int c = (threadIdx.x & 127) << 2;
    float k = kv[row];
    float km1 = 1.0f - k;
    float4 fa = *(const float4*)(feat_l + (size_t)ia[row] * HID2 + c);
    float4 fb = *(const float4*)(feat_l + (size_t)ib[row] * HID2 + c);
    float4 o;
    o.x = k * fa.x + km1 * fb.x;
    o.y = k * fa.y + km1 * fb.y;
    o.z = k * fa.z + km1 * fb.z;
    o.w = k * fa.w + km1 * fb.w;
    *(float4*)(out_comb + (size_t)row * HID2 + c) = o;
  } else {
    int wave = threadIdx.x >> 6;
    int lane = threadIdx.x & 63;
    int row = (b - COMB_BLOCKS) * 4 + wave;
    const float* f = feat_l + (size_t)row * HID2;
    float s = 0.f;
#pragma unroll
    for (int j = 0; j < HID2 / 64; ++j) s = fmaf(f[lane + j * 64], W3[lane + j * 64], s);
#pragma unroll
    for (int off = 32; off; off >>= 1) s += __shfl_down(s, off);
    if (lane == 0) out_yhat[row] = s + b3[0];
  }
}

// ---------------------------------------------------------------------------
extern "C" void kernel_launch(void* const* d_in, const int* in_sizes, int n_in,
                              void* d_out, int out_size, void* d_ws, size_t ws_size,
                              hipStream_t stream)
{
  const float* X_l = (const float*)d_in[0];
  const float* y_l = (const float*)d_in[1];
  const float* X_u = (const float*)d_in[2];
  const float* y_u = (const float*)d_in[3];
  const float* W1  = (const float*)d_in[4];
  const float* b1  = (const float*)d_in[5];
  const float* W2  = (const float*)d_in[6];
  const float* b2  = (const float*)d_in[7];
  const float* W3  = (const float*)d_in[8];
  const float* b3  = (const float*)d_in[9];

  float* out_featu = (float*)d_out;
  float* out_comb  = out_featu + (size_t)SUNL * HID2;
  float* out_yhat  = out_comb + (size_t)SUNL * HID2;

  // Workspace (~174 MB): X_bf = [Xl|Xu] contig, H_bf = [Hl|Hu] contig
  unsigned short* X_bf  = (unsigned short*)d_ws;                 // [24576][1024]
  unsigned short* W1T   = X_bf + (size_t)MTOT * DIMX;
  unsigned short* W2T   = W1T + (size_t)HID1 * DIMX;
  unsigned short* H_bf  = W2T + (size_t)HID2 * HID1;             // [24576][2048]
  float* feat_l = (float*)(H_bf + (size_t)MTOT * HID1);
  int*   ai = (int*)(feat_l + (size_t)SLAB * HID2);
  int*   bi = ai + SUNL;
  float* kv = (float*)(bi + SUNL);

  prep_kernel<<<dim3(PREP_BLOCKS), dim3(256), 0, stream>>>(
      X_l, X_u, W1, W2, y_l, y_u, X_bf, W1T, W2T, ai, bi, kv);

  // layer 1 (merged l+u): H = relu(X @ W1 + b1) -> bf16  [768 blocks x 512]
  gemm_bt_256<1, 1><<<dim3((HID1 / 256) * (MTOT / 256)), dim3(512), 0, stream>>>(
      X_bf, W1T, b1, H_bf, H_bf, MTOT /*no split*/, MTOT, HID1, DIMX);

  // layer 2 (merged l+u): feat = relu(H @ W2 + b2) -> fp32, split dest [192 blocks]
  gemm_bt_256<0, 1><<<dim3((HID2 / 256) * (MTOT / 256)), dim3(512), 0, stream>>>(
      H_bf, W2T, b2, feat_l, out_featu, SLAB, MTOT, HID2, HID1);

  post_kernel<<<dim3(POST_BLOCKS), dim3(256), 0, stream>>>(
      feat_l, W3, b3, ai, bi, kv, out_comb, out_yhat);
}